// Round 1
// baseline (27678.220 us; speedup 1.0000x reference)
//
#include <hip/hip_runtime.h>
#include <hip/hip_bf16.h>

#define SS 50
#define TT 50
#define BB 64
#define SRCV 36616
#define TRGV 23262
#define EE 300
#define EH 512
#define DH 1024
// decoder concat K: c_t(1024) | e(300) | h(1024) = 2348, padded to 2368 (37*64)
#define DKPAD 2368

__global__ void k_zero(float* __restrict__ p, long n) {
  long i = (long)blockIdx.x * 256 + threadIdx.x;
  if (i < n) p[i] = 0.f;
}

__global__ void k_embed(const int* __restrict__ src, const float* __restrict__ emb,
                        float* __restrict__ x) {
  int id = blockIdx.x * 256 + threadIdx.x;
  if (id >= SS * BB * EE) return;
  int sb = id / EE, e = id % EE;
  x[id] = emb[(long)src[sb] * EE + e];
}

// W_cat[row, 0:1324]=dec_W_ih ; [1324:2348]=dec_W_hh ; [2348:2368]=0
__global__ void k_wcat(const float* __restrict__ Wih, const float* __restrict__ Whh,
                       float* __restrict__ Wcat) {
  long id = (long)blockIdx.x * 256 + threadIdx.x;
  if (id >= (long)4096 * DKPAD) return;
  int row = id / DKPAD, k = id % DKPAD;
  float v;
  if (k < 1324) v = Wih[(long)row * 1324 + k];
  else if (k < 2348) v = Whh[(long)row * 1024 + (k - 1324)];
  else v = 0.f;
  Wcat[id] = v;
}

// generic tiled fp32 GEMM: C[M,N] = A[M,K] * W[N,K]^T (+bias). rev remaps A rows
// (per-64-row group reversal, used for the backward-direction encoder input GEMM).
__global__ __launch_bounds__(256) void k_gemm_big(
    const float* __restrict__ A, const float* __restrict__ W,
    const float* __restrict__ bias, float* __restrict__ C,
    int M, int N, int K, int rev) {
  __shared__ float As[16][65];
  __shared__ float Bs[16][65];
  int tid = threadIdx.x;
  int tx = tid & 15, ty = tid >> 4;
  int m0 = blockIdx.y * 64, n0 = blockIdx.x * 64;
  int Srows = M >> 6;
  float acc[4][4] = {};
  for (int k0 = 0; k0 < K; k0 += 16) {
    for (int i = 0; i < 4; ++i) {
      int idx = tid + 256 * i;
      int r = idx >> 4, kk = idx & 15;
      int m = m0 + r;
      float v = 0.f;
      if (m < M && k0 + kk < K) {
        int ar = rev ? (((Srows - 1 - (m >> 6)) << 6) + (m & 63)) : m;
        v = A[(long)ar * K + k0 + kk];
      }
      As[kk][r] = v;
    }
    for (int i = 0; i < 4; ++i) {
      int idx = tid + 256 * i;
      int r = idx >> 4, kk = idx & 15;
      int n = n0 + r;
      float v = 0.f;
      if (n < N && k0 + kk < K) v = W[(long)n * K + k0 + kk];
      Bs[kk][r] = v;
    }
    __syncthreads();
    for (int kk = 0; kk < 16; ++kk) {
      float a[4], bv[4];
      for (int r = 0; r < 4; ++r) a[r] = As[kk][ty * 4 + r];
      for (int c = 0; c < 4; ++c) bv[c] = Bs[kk][tx * 4 + c];
      for (int r = 0; r < 4; ++r)
        for (int c = 0; c < 4; ++c) acc[r][c] += a[r] * bv[c];
    }
    __syncthreads();
  }
  for (int r = 0; r < 4; ++r) {
    int m = m0 + ty * 4 + r;
    if (m >= M) continue;
    for (int c = 0; c < 4; ++c) {
      int n = n0 + tx * 4 + c;
      if (n >= N) continue;
      float v = acc[r][c];
      if (bias) v += bias[n];
      C[(long)m * N + n] = v;
    }
  }
}

// encoder LSTM step: gates[b,j+g*512] = xW[b, j+g*512] + sum_k h[b,k] W_hh[j+g*512,k]
// then pointwise LSTM update. blockDim (64,4): thread (b,jj), block covers 4 cols.
__global__ __launch_bounds__(256) void k_enc_step(
    const float* __restrict__ h_prev, float* __restrict__ c,
    const float* __restrict__ W_hh, const float* __restrict__ xW,
    float* __restrict__ h_next, float* __restrict__ hs_dst) {
  __shared__ float As[64][65];
  __shared__ float Ws[16][64];
  int b = threadIdx.x, jj = threadIdx.y;
  int tid = jj * 64 + b;
  int j0 = blockIdx.x * 4;
  float acc[4] = {0.f, 0.f, 0.f, 0.f};
  for (int k0 = 0; k0 < EH; k0 += 64) {
    for (int i = 0; i < 16; ++i) {
      int idx = tid + 256 * i;
      int r = idx >> 6, kk = idx & 63;
      As[r][kk] = h_prev[r * EH + k0 + kk];
    }
    for (int i = 0; i < 4; ++i) {
      int idx = tid + 256 * i;
      int r = idx >> 6, kk = idx & 63;
      int grow = j0 + (r & 3) + (r >> 2) * EH;
      Ws[r][kk] = W_hh[grow * EH + k0 + kk];
    }
    __syncthreads();
    for (int kk = 0; kk < 64; ++kk) {
      float a = As[b][kk];
      acc[0] += a * Ws[jj][kk];
      acc[1] += a * Ws[4 + jj][kk];
      acc[2] += a * Ws[8 + jj][kk];
      acc[3] += a * Ws[12 + jj][kk];
    }
    __syncthreads();
  }
  int j = j0 + jj;
  float gi = acc[0] + xW[b * 2048 + j];
  float gf = acc[1] + xW[b * 2048 + j + 512];
  float gg = acc[2] + xW[b * 2048 + j + 1024];
  float go = acc[3] + xW[b * 2048 + j + 1536];
  float ii = 1.f / (1.f + expf(-gi));
  float ff = 1.f / (1.f + expf(-gf));
  float gt = tanhf(gg);
  float oo = 1.f / (1.f + expf(-go));
  float cn = ff * c[b * EH + j] + ii * gt;
  float hn = oo * tanhf(cn);
  c[b * EH + j] = cn;
  h_next[b * EH + j] = hn;
  hs_dst[b * 1024 + j] = hn;
}

// decoder LSTM gates over padded concat input (K=2368), W_cat(4096,2368), + update.
__global__ __launch_bounds__(256) void k_dec_step(
    const float* __restrict__ dec_in, const float* __restrict__ Wcat,
    const float* __restrict__ bias, float* __restrict__ c,
    float* __restrict__ h_next, float* __restrict__ hall) {
  __shared__ float As[64][65];
  __shared__ float Ws[16][64];
  int b = threadIdx.x, jj = threadIdx.y;
  int tid = jj * 64 + b;
  int j0 = blockIdx.x * 4;
  float acc[4] = {0.f, 0.f, 0.f, 0.f};
  for (int k0 = 0; k0 < DKPAD; k0 += 64) {
    for (int i = 0; i < 16; ++i) {
      int idx = tid + 256 * i;
      int r = idx >> 6, kk = idx & 63;
      As[r][kk] = dec_in[r * DKPAD + k0 + kk];
    }
    for (int i = 0; i < 4; ++i) {
      int idx = tid + 256 * i;
      int r = idx >> 6, kk = idx & 63;
      int grow = j0 + (r & 3) + (r >> 2) * 1024;
      Ws[r][kk] = Wcat[(long)grow * DKPAD + k0 + kk];
    }
    __syncthreads();
    for (int kk = 0; kk < 64; ++kk) {
      float a = As[b][kk];
      acc[0] += a * Ws[jj][kk];
      acc[1] += a * Ws[4 + jj][kk];
      acc[2] += a * Ws[8 + jj][kk];
      acc[3] += a * Ws[12 + jj][kk];
    }
    __syncthreads();
  }
  int j = j0 + jj;
  float gi = acc[0] + bias[j];
  float gf = acc[1] + bias[j + 1024];
  float gg = acc[2] + bias[j + 2048];
  float go = acc[3] + bias[j + 3072];
  float ii = 1.f / (1.f + expf(-gi));
  float ff = 1.f / (1.f + expf(-gf));
  float gt = tanhf(gg);
  float oo = 1.f / (1.f + expf(-go));
  float cn = ff * c[b * 1024 + j] + ii * gt;
  float hn = oo * tanhf(cn);
  c[b * 1024 + j] = cn;
  h_next[b * 1024 + j] = hn;
  hall[b * 1024 + j] = hn;
}

// M=64 GEMM: C[b, n0..] = [A1|A2](64, K1+K2) * W(N, K1+K2)^T, optional tanh.
// blockDim (64,4); each block covers 16 output cols.
__global__ __launch_bounds__(256) void k_gemm64(
    const float* __restrict__ A1, int lda1, int K1,
    const float* __restrict__ A2, int lda2, int K2,
    const float* __restrict__ W, int ldw,
    float* __restrict__ C, int ldc, int do_tanh) {
  __shared__ float As[64][65];
  __shared__ float Ws[16][64];
  int b = threadIdx.x, jj = threadIdx.y;
  int tid = jj * 64 + b;
  int n0 = blockIdx.x * 16;
  float acc[4] = {0.f, 0.f, 0.f, 0.f};
  for (int seg = 0; seg < 2; ++seg) {
    const float* A = seg ? A2 : A1;
    int lda = seg ? lda2 : lda1;
    int K = seg ? K2 : K1;
    int koff = seg ? K1 : 0;
    for (int k0 = 0; k0 < K; k0 += 64) {
      for (int i = 0; i < 16; ++i) {
        int idx = tid + 256 * i;
        int r = idx >> 6, kk = idx & 63;
        As[r][kk] = A[r * lda + k0 + kk];
      }
      for (int i = 0; i < 4; ++i) {
        int idx = tid + 256 * i;
        int r = idx >> 6, kk = idx & 63;
        Ws[r][kk] = W[(long)(n0 + r) * ldw + koff + k0 + kk];
      }
      __syncthreads();
      for (int kk = 0; kk < 64; ++kk) {
        float a = As[b][kk];
        acc[0] += a * Ws[jj][kk];
        acc[1] += a * Ws[4 + jj][kk];
        acc[2] += a * Ws[8 + jj][kk];
        acc[3] += a * Ws[12 + jj][kk];
      }
      __syncthreads();
    }
  }
  for (int m = 0; m < 4; ++m) {
    float v = acc[m];
    if (do_tanh) v = tanhf(v);
    C[b * ldc + n0 + jj + 4 * m] = v;
  }
}

// decoder initial state: reshape(stack([hf,hb],0),(64,1024)) flat-index remap
__global__ void k_build_h0(const float* __restrict__ hf, const float* __restrict__ hb,
                           const float* __restrict__ cf, const float* __restrict__ cb,
                           float* __restrict__ h0, float* __restrict__ c0) {
  int id = blockIdx.x * 256 + threadIdx.x;  // 65536
  int dir = id >> 15;
  int b = (id >> 9) & 63;
  int j = id & 511;
  h0[id] = dir ? hb[b * EH + j] : hf[b * EH + j];
  c0[id] = dir ? cb[b * EH + j] : cf[b * EH + j];
}

// scores[s,b] = dot(hs[s,b,:], q[b,:]); softmax over b (axis=1 in reference!)
__global__ __launch_bounds__(256) void k_scores(
    const float* __restrict__ hs, const float* __restrict__ q,
    float* __restrict__ attw) {
  int s = blockIdx.x;
  int tid = threadIdx.x;
  int b = tid >> 2, l = tid & 3;
  const float* hrow = hs + (long)s * (BB * 1024) + b * 1024;
  const float* qrow = q + b * 1024;
  float p = 0.f;
  for (int d = l; d < 1024; d += 4) p += hrow[d] * qrow[d];
  p += __shfl_xor(p, 1);
  p += __shfl_xor(p, 2);
  __shared__ float sc[64];
  if (l == 0) sc[b] = p;
  __syncthreads();
  if (tid < 64) {
    float v = sc[tid];
    float m = v;
    for (int o = 32; o > 0; o >>= 1) m = fmaxf(m, __shfl_xor(m, o));
    float e = expf(v - m);
    float su = e;
    for (int o = 32; o > 0; o >>= 1) su += __shfl_xor(su, o);
    attw[s * BB + tid] = e / su;
  }
}

// s_t[b,d] = sum_s attw[s,b] * hs[s,b,d]
__global__ void k_st(const float* __restrict__ hs, const float* __restrict__ attw,
                     float* __restrict__ s_t) {
  int id = blockIdx.x * 256 + threadIdx.x;  // 65536
  int b = id >> 10;
  float acc = 0.f;
  for (int s = 0; s < SS; ++s) acc += attw[s * BB + b] * hs[(long)s * (BB * 1024) + id];
  s_t[id] = acc;
}

// fill dec_in cols 1024..2347: e = emb_de[trg[t,b]] then h_prev
__global__ void k_copy_eh(const int* __restrict__ trg_t, const float* __restrict__ emb_de,
                          const float* __restrict__ h_prev, float* __restrict__ dec_in) {
  int id = blockIdx.x * 256 + threadIdx.x;
  if (id >= BB * 1324) return;
  int b = id / 1324, k = id % 1324;
  float v;
  if (k < 300) v = emb_de[(long)trg_t[b] * EE + k];
  else v = h_prev[b * 1024 + (k - 300)];
  dec_in[b * DKPAD + 1024 + k] = v;
}

// in-place log-softmax over vocab for rows 64..3199 of out
__global__ __launch_bounds__(256) void k_logsoftmax(float* __restrict__ out) {
  int r = blockIdx.x;
  float* p = out + (long)(BB + r) * TRGV;
  int tid = threadIdx.x;
  __shared__ float red[256];
  float m = -1e30f;
  for (int i = tid; i < TRGV; i += 256) m = fmaxf(m, p[i]);
  red[tid] = m;
  __syncthreads();
  for (int s = 128; s > 0; s >>= 1) {
    if (tid < s) red[tid] = fmaxf(red[tid], red[tid + s]);
    __syncthreads();
  }
  m = red[0];
  __syncthreads();
  float sum = 0.f;
  for (int i = tid; i < TRGV; i += 256) sum += expf(p[i] - m);
  red[tid] = sum;
  __syncthreads();
  for (int s = 128; s > 0; s >>= 1) {
    if (tid < s) red[tid] += red[tid + s];
    __syncthreads();
  }
  float lse = m + logf(red[0]);
  for (int i = tid; i < TRGV; i += 256) p[i] -= lse;
}

extern "C" void kernel_launch(void* const* d_in, const int* in_sizes, int n_in,
                              void* d_out, int out_size, void* d_ws, size_t ws_size,
                              hipStream_t stream) {
  const int* src = (const int*)d_in[0];
  const int* trg = (const int*)d_in[1];
  const float* emb_en = (const float*)d_in[2];
  const float* emb_de = (const float*)d_in[3];
  const float* eWih_f = (const float*)d_in[4];
  const float* eWhh_f = (const float*)d_in[5];
  const float* eb_f = (const float*)d_in[6];
  const float* eWih_b = (const float*)d_in[7];
  const float* eWhh_b = (const float*)d_in[8];
  const float* eb_b = (const float*)d_in[9];
  const float* dWih = (const float*)d_in[10];
  const float* dWhh = (const float*)d_in[11];
  const float* db = (const float*)d_in[12];
  const float* Wgen = (const float*)d_in[13];
  const float* bgen = (const float*)d_in[14];
  const float* Wi = (const float*)d_in[15];
  const float* Wo = (const float*)d_in[16];
  float* out = (float*)d_out;

  float* p = (float*)d_ws;
  float* x_enc = p; p += SS * BB * EE;          // 960000
  float* xW_f = p; p += (long)SS * BB * 2048;   // 6553600
  float* xW_b = p; p += (long)SS * BB * 2048;
  float* hs = p; p += (long)SS * BB * 1024;     // 3276800
  float* hf0 = p; p += BB * EH;
  float* cf = p; p += BB * EH;
  float* hb0 = p; p += BB * EH;
  float* cb = p; p += BB * EH;
  float* hf1 = p; p += BB * EH;
  float* hb1 = p; p += BB * EH;
  float* hd0 = p; p += BB * DH;
  float* hd1 = p; p += BB * DH;
  float* cd = p; p += BB * DH;
  float* qb = p; p += BB * DH;
  float* attw = p; p += SS * BB;
  float* stb = p; p += BB * DH;
  float* dec_in = p; p += BB * DKPAD;           // 151552
  float* Wcat = p; p += (long)4096 * DKPAD;     // 9699328
  float* Hall = p; p += (long)(TT - 1) * BB * DH;

  dim3 b256(256);
  dim3 b64x4(64, 4);

  // ---- setup ----
  k_embed<<<dim3((SS * BB * EE + 255) / 256), b256, 0, stream>>>(src, emb_en, x_enc);
  k_wcat<<<dim3((int)(((long)4096 * DKPAD + 255) / 256)), b256, 0, stream>>>(dWih, dWhh, Wcat);
  k_zero<<<dim3((4 * BB * EH + 255) / 256), b256, 0, stream>>>(hf0, 4 * BB * EH);  // hf0,cf,hb0,cb
  k_zero<<<dim3((BB * DKPAD + 255) / 256), b256, 0, stream>>>(dec_in, BB * DKPAD);
  k_zero<<<dim3((BB * TRGV + 255) / 256), b256, 0, stream>>>(out, (long)BB * TRGV);  // out[0]=0

  // ---- encoder input GEMMs: xW = x @ W_ih^T + b  (rev=1 reverses the sequence) ----
  k_gemm_big<<<dim3(2048 / 64, (SS * BB) / 64), b256, 0, stream>>>(
      x_enc, eWih_f, eb_f, xW_f, SS * BB, 2048, EE, 0);
  k_gemm_big<<<dim3(2048 / 64, (SS * BB) / 64), b256, 0, stream>>>(
      x_enc, eWih_b, eb_b, xW_b, SS * BB, 2048, EE, 1);

  // ---- encoder recurrences ----
  {
    float* hp = hf0;
    float* hn = hf1;
    for (int s = 0; s < SS; ++s) {
      k_enc_step<<<dim3(EH / 4), b64x4, 0, stream>>>(
          hp, cf, eWhh_f, xW_f + (long)s * BB * 2048, hn, hs + (long)s * BB * 1024);
      float* t = hp; hp = hn; hn = t;
    }
    float* hbp = hb0;
    float* hbn = hb1;
    for (int s = 0; s < SS; ++s) {
      k_enc_step<<<dim3(EH / 4), b64x4, 0, stream>>>(
          hbp, cb, eWhh_b, xW_b + (long)s * BB * 2048, hbn,
          hs + (long)(SS - 1 - s) * BB * 1024 + EH);
      float* t = hbp; hbp = hbn; hbn = t;
    }
    // after even # of swaps final h is back in hp/hbp
    k_build_h0<<<dim3(256), b256, 0, stream>>>(hp, hbp, cf, cb, hd0, cd);
  }

  // ---- decoder loop ----
  float* hc = hd0;
  float* hx = hd1;
  for (int t = 0; t < TT - 1; ++t) {
    // q = h @ W_i^T
    k_gemm64<<<dim3(DH / 16), b64x4, 0, stream>>>(
        hc, DH, DH, (const float*)nullptr, 0, 0, Wi, DH, qb, DH, 0);
    k_scores<<<dim3(SS), b256, 0, stream>>>(hs, qb, attw);
    k_st<<<dim3(256), b256, 0, stream>>>(hs, attw, stb);
    // c_t = tanh([s_t | h] @ W_o^T) -> dec_in cols 0..1023
    k_gemm64<<<dim3(DH / 16), b64x4, 0, stream>>>(
        stb, DH, DH, hc, DH, DH, Wo, 2 * DH, dec_in, DKPAD, 1);
    k_copy_eh<<<dim3((BB * 1324 + 255) / 256), b256, 0, stream>>>(
        trg + t * BB, emb_de, hc, dec_in);
    k_dec_step<<<dim3(DH / 4), b64x4, 0, stream>>>(
        dec_in, Wcat, db, cd, hx, Hall + (long)t * BB * DH);
    float* tmp = hc; hc = hx; hx = tmp;
  }

  // ---- generator: logits for all 49 steps in one GEMM, then log-softmax ----
  k_gemm_big<<<dim3((TRGV + 63) / 64, ((TT - 1) * BB) / 64), b256, 0, stream>>>(
      Hall, Wgen, bgen, out + (long)BB * TRGV, (TT - 1) * BB, TRGV, DH, 0);
  k_logsoftmax<<<dim3((TT - 1) * BB), b256, 0, stream>>>(out);
}

// Round 2
// 24392.697 us; speedup vs baseline: 1.1347x; 1.1347x over previous
//
#include <hip/hip_runtime.h>
#include <hip/hip_bf16.h>

#define SS 50
#define TT 50
#define BB 64
#define SRCV 36616
#define TRGV 23262
#define EE 300
#define EH 512
#define DH 1024
// decoder concat K: c_t(1024) | e(300) | h(1024) = 2348, padded to 2368 (37*64)
#define DKPAD 2368

// generator GEMM geometry (bf16 MFMA)
#define GMRE 3136    // real M = 49*64
#define GMP 3200     // padded M (25 tiles of 128)
#define GK 1024
#define GNRE TRGV
#define GNP 23296    // padded N (182 tiles of 128)

typedef short bf16x8 __attribute__((ext_vector_type(8)));
typedef float f32x4 __attribute__((ext_vector_type(4)));

__device__ __forceinline__ void glds16(const void* g, void* l) {
  __builtin_amdgcn_global_load_lds(
      (const __attribute__((address_space(1))) void*)g,
      (__attribute__((address_space(3))) void*)l, 16, 0, 0);
}

__global__ void k_zero(float* __restrict__ p, long n) {
  long i = (long)blockIdx.x * 256 + threadIdx.x;
  if (i < n) p[i] = 0.f;
}

__global__ void k_zero_bf(__hip_bfloat16* __restrict__ p, long n) {
  long i = (long)blockIdx.x * 256 + threadIdx.x;
  if (i < n) p[i] = __float2bfloat16(0.f);
}

__global__ void k_embed(const int* __restrict__ src, const float* __restrict__ emb,
                        float* __restrict__ x) {
  int id = blockIdx.x * 256 + threadIdx.x;
  if (id >= SS * BB * EE) return;
  int sb = id / EE, e = id % EE;
  x[id] = emb[(long)src[sb] * EE + e];
}

// W_cat[row, 0:1324]=dec_W_ih ; [1324:2348]=dec_W_hh ; [2348:2368]=0
__global__ void k_wcat(const float* __restrict__ Wih, const float* __restrict__ Whh,
                       float* __restrict__ Wcat) {
  long id = (long)blockIdx.x * 256 + threadIdx.x;
  if (id >= (long)4096 * DKPAD) return;
  int row = id / DKPAD, k = id % DKPAD;
  float v;
  if (k < 1324) v = Wih[(long)row * 1324 + k];
  else if (k < 2348) v = Whh[(long)row * 1024 + (k - 1324)];
  else v = 0.f;
  Wcat[id] = v;
}

// convert W (row-major, K cols) to bf16 with zero row padding
__global__ void k_tobf16_pad(const float* __restrict__ W, __hip_bfloat16* __restrict__ Wb,
                             long nrow_real, long nrow_pad, int K) {
  long id = (long)blockIdx.x * 256 + threadIdx.x;
  if (id >= nrow_pad * K) return;
  long r = id / K;
  Wb[id] = __float2bfloat16(r < nrow_real ? W[id] : 0.f);
}

// generic tiled fp32 GEMM: C[M,N] = A[M,K] * W[N,K]^T (+bias). rev remaps A rows
__global__ __launch_bounds__(256) void k_gemm_big(
    const float* __restrict__ A, const float* __restrict__ W,
    const float* __restrict__ bias, float* __restrict__ C,
    int M, int N, int K, int rev) {
  __shared__ float As[16][65];
  __shared__ float Bs[16][65];
  int tid = threadIdx.x;
  int tx = tid & 15, ty = tid >> 4;
  int m0 = blockIdx.y * 64, n0 = blockIdx.x * 64;
  int Srows = M >> 6;
  float acc[4][4] = {};
  for (int k0 = 0; k0 < K; k0 += 16) {
    for (int i = 0; i < 4; ++i) {
      int idx = tid + 256 * i;
      int r = idx >> 4, kk = idx & 15;
      int m = m0 + r;
      float v = 0.f;
      if (m < M && k0 + kk < K) {
        int ar = rev ? (((Srows - 1 - (m >> 6)) << 6) + (m & 63)) : m;
        v = A[(long)ar * K + k0 + kk];
      }
      As[kk][r] = v;
    }
    for (int i = 0; i < 4; ++i) {
      int idx = tid + 256 * i;
      int r = idx >> 4, kk = idx & 15;
      int n = n0 + r;
      float v = 0.f;
      if (n < N && k0 + kk < K) v = W[(long)n * K + k0 + kk];
      Bs[kk][r] = v;
    }
    __syncthreads();
    for (int kk = 0; kk < 16; ++kk) {
      float a[4], bv[4];
      for (int r = 0; r < 4; ++r) a[r] = As[kk][ty * 4 + r];
      for (int c = 0; c < 4; ++c) bv[c] = Bs[kk][tx * 4 + c];
      for (int r = 0; r < 4; ++r)
        for (int c = 0; c < 4; ++c) acc[r][c] += a[r] * bv[c];
    }
    __syncthreads();
  }
  for (int r = 0; r < 4; ++r) {
    int m = m0 + ty * 4 + r;
    if (m >= M) continue;
    for (int c = 0; c < 4; ++c) {
      int n = n0 + tx * 4 + c;
      if (n >= N) continue;
      float v = acc[r][c];
      if (bias) v += bias[n];
      C[(long)m * N + n] = v;
    }
  }
}

// ---- bf16 MFMA generator GEMM: C[m,n] = sum_k A[m,k]*Bw[n,k] + bias[n] ----
// A: [GMP][GK] bf16 row-major (zero-padded rows). Bw: [GNP][GK] bf16 (zero-padded).
// 128x128 tile, BK=32, 4 waves each computing 64x64. m97-style structure.
__global__ __launch_bounds__(256) void k_gen_mfma(
    const __hip_bfloat16* __restrict__ A, const __hip_bfloat16* __restrict__ Bw,
    const float* __restrict__ bias, float* __restrict__ C) {
  __shared__ __hip_bfloat16 As[128 * 32];
  __shared__ __hip_bfloat16 Bs[128 * 32];
  int tid = threadIdx.x;
  int lane = tid & 63, w = tid >> 6;
  long m0 = (long)blockIdx.y * 128, n0 = (long)blockIdx.x * 128;

  // staging addressing: wave w covers rows w*32 .. w*32+31 of each tile
  int srow = lane >> 2;            // 0..15
  int scol = (lane & 3) * 8;       // bf16 units (16B chunks)
  const __hip_bfloat16* gA0 = A + (m0 + w * 32 + srow) * GK + scol;
  const __hip_bfloat16* gA1 = gA0 + 16 * GK;
  const __hip_bfloat16* gB0 = Bw + (n0 + w * 32 + srow) * GK + scol;
  const __hip_bfloat16* gB1 = gB0 + 16 * GK;
  char* lA0 = (char*)As + w * 2048;
  char* lA1 = lA0 + 1024;
  char* lB0 = (char*)Bs + w * 2048;
  char* lB1 = lB0 + 1024;

  // compute addressing
  int wm = (w >> 1) * 64, wn = (w & 1) * 64;
  int fr = lane & 15;
  int kc = (lane >> 4) * 8;
  f32x4 acc[4][4] = {};

  for (int kt = 0; kt < GK / 32; ++kt) {
    int k0 = kt * 32;
    glds16(gA0 + k0, lA0);
    glds16(gA1 + k0, lA1);
    glds16(gB0 + k0, lB0);
    glds16(gB1 + k0, lB1);
    __syncthreads();  // drains vmcnt -> staged data visible
    bf16x8 a[4], b[4];
    for (int mi = 0; mi < 4; ++mi)
      a[mi] = *(const bf16x8*)(As + (wm + mi * 16 + fr) * 32 + kc);
    for (int ni = 0; ni < 4; ++ni)
      b[ni] = *(const bf16x8*)(Bs + (wn + ni * 16 + fr) * 32 + kc);
    for (int mi = 0; mi < 4; ++mi)
      for (int ni = 0; ni < 4; ++ni)
        acc[mi][ni] = __builtin_amdgcn_mfma_f32_16x16x32_bf16(a[mi], b[ni], acc[mi][ni], 0, 0, 0);
    __syncthreads();  // before next stage overwrites LDS
  }

  for (int mi = 0; mi < 4; ++mi) {
    for (int ni = 0; ni < 4; ++ni) {
      int n = (int)n0 + wn + ni * 16 + (lane & 15);
      if (n >= GNRE) continue;
      float bv = bias[n];
      for (int r = 0; r < 4; ++r) {
        int m = (int)m0 + wm + mi * 16 + (lane >> 4) * 4 + r;
        if (m < GMRE) C[(long)m * TRGV + n] = acc[mi][ni][r] + bv;
      }
    }
  }
}

// encoder LSTM step
__global__ __launch_bounds__(256) void k_enc_step(
    const float* __restrict__ h_prev, float* __restrict__ c,
    const float* __restrict__ W_hh, const float* __restrict__ xW,
    float* __restrict__ h_next, float* __restrict__ hs_dst) {
  __shared__ float As[64][65];
  __shared__ float Ws[16][64];
  int b = threadIdx.x, jj = threadIdx.y;
  int tid = jj * 64 + b;
  int j0 = blockIdx.x * 4;
  float acc[4] = {0.f, 0.f, 0.f, 0.f};
  for (int k0 = 0; k0 < EH; k0 += 64) {
    for (int i = 0; i < 16; ++i) {
      int idx = tid + 256 * i;
      int r = idx >> 6, kk = idx & 63;
      As[r][kk] = h_prev[r * EH + k0 + kk];
    }
    for (int i = 0; i < 4; ++i) {
      int idx = tid + 256 * i;
      int r = idx >> 6, kk = idx & 63;
      int grow = j0 + (r & 3) + (r >> 2) * EH;
      Ws[r][kk] = W_hh[grow * EH + k0 + kk];
    }
    __syncthreads();
    for (int kk = 0; kk < 64; ++kk) {
      float a = As[b][kk];
      acc[0] += a * Ws[jj][kk];
      acc[1] += a * Ws[4 + jj][kk];
      acc[2] += a * Ws[8 + jj][kk];
      acc[3] += a * Ws[12 + jj][kk];
    }
    __syncthreads();
  }
  int j = j0 + jj;
  float gi = acc[0] + xW[b * 2048 + j];
  float gf = acc[1] + xW[b * 2048 + j + 512];
  float gg = acc[2] + xW[b * 2048 + j + 1024];
  float go = acc[3] + xW[b * 2048 + j + 1536];
  float ii = 1.f / (1.f + expf(-gi));
  float ff = 1.f / (1.f + expf(-gf));
  float gt = tanhf(gg);
  float oo = 1.f / (1.f + expf(-go));
  float cn = ff * c[b * EH + j] + ii * gt;
  float hn = oo * tanhf(cn);
  c[b * EH + j] = cn;
  h_next[b * EH + j] = hn;
  hs_dst[b * 1024 + j] = hn;
}

// decoder LSTM gates over padded concat input; writes h (fp32) + Hall (bf16)
__global__ __launch_bounds__(256) void k_dec_step(
    const float* __restrict__ dec_in, const float* __restrict__ Wcat,
    const float* __restrict__ bias, float* __restrict__ c,
    float* __restrict__ h_next, __hip_bfloat16* __restrict__ hall) {
  __shared__ float As[64][65];
  __shared__ float Ws[16][64];
  int b = threadIdx.x, jj = threadIdx.y;
  int tid = jj * 64 + b;
  int j0 = blockIdx.x * 4;
  float acc[4] = {0.f, 0.f, 0.f, 0.f};
  for (int k0 = 0; k0 < DKPAD; k0 += 64) {
    for (int i = 0; i < 16; ++i) {
      int idx = tid + 256 * i;
      int r = idx >> 6, kk = idx & 63;
      As[r][kk] = dec_in[r * DKPAD + k0 + kk];
    }
    for (int i = 0; i < 4; ++i) {
      int idx = tid + 256 * i;
      int r = idx >> 6, kk = idx & 63;
      int grow = j0 + (r & 3) + (r >> 2) * 1024;
      Ws[r][kk] = Wcat[(long)grow * DKPAD + k0 + kk];
    }
    __syncthreads();
    for (int kk = 0; kk < 64; ++kk) {
      float a = As[b][kk];
      acc[0] += a * Ws[jj][kk];
      acc[1] += a * Ws[4 + jj][kk];
      acc[2] += a * Ws[8 + jj][kk];
      acc[3] += a * Ws[12 + jj][kk];
    }
    __syncthreads();
  }
  int j = j0 + jj;
  float gi = acc[0] + bias[j];
  float gf = acc[1] + bias[j + 1024];
  float gg = acc[2] + bias[j + 2048];
  float go = acc[3] + bias[j + 3072];
  float ii = 1.f / (1.f + expf(-gi));
  float ff = 1.f / (1.f + expf(-gf));
  float gt = tanhf(gg);
  float oo = 1.f / (1.f + expf(-go));
  float cn = ff * c[b * 1024 + j] + ii * gt;
  float hn = oo * tanhf(cn);
  c[b * 1024 + j] = cn;
  h_next[b * 1024 + j] = hn;
  hall[b * 1024 + j] = __float2bfloat16(hn);
}

// M=64 GEMM: C[b, n0..] = [A1|A2](64, K1+K2) * W(N, K1+K2)^T, optional tanh.
__global__ __launch_bounds__(256) void k_gemm64(
    const float* __restrict__ A1, int lda1, int K1,
    const float* __restrict__ A2, int lda2, int K2,
    const float* __restrict__ W, int ldw,
    float* __restrict__ C, int ldc, int do_tanh) {
  __shared__ float As[64][65];
  __shared__ float Ws[16][64];
  int b = threadIdx.x, jj = threadIdx.y;
  int tid = jj * 64 + b;
  int n0 = blockIdx.x * 16;
  float acc[4] = {0.f, 0.f, 0.f, 0.f};
  for (int seg = 0; seg < 2; ++seg) {
    const float* A = seg ? A2 : A1;
    int lda = seg ? lda2 : lda1;
    int K = seg ? K2 : K1;
    int koff = seg ? K1 : 0;
    for (int k0 = 0; k0 < K; k0 += 64) {
      for (int i = 0; i < 16; ++i) {
        int idx = tid + 256 * i;
        int r = idx >> 6, kk = idx & 63;
        As[r][kk] = A[r * lda + k0 + kk];
      }
      for (int i = 0; i < 4; ++i) {
        int idx = tid + 256 * i;
        int r = idx >> 6, kk = idx & 63;
        Ws[r][kk] = W[(long)(n0 + r) * ldw + koff + k0 + kk];
      }
      __syncthreads();
      for (int kk = 0; kk < 64; ++kk) {
        float a = As[b][kk];
        acc[0] += a * Ws[jj][kk];
        acc[1] += a * Ws[4 + jj][kk];
        acc[2] += a * Ws[8 + jj][kk];
        acc[3] += a * Ws[12 + jj][kk];
      }
      __syncthreads();
    }
  }
  for (int m = 0; m < 4; ++m) {
    float v = acc[m];
    if (do_tanh) v = tanhf(v);
    C[b * ldc + n0 + jj + 4 * m] = v;
  }
}

// decoder initial state: reshape(stack([hf,hb],0),(64,1024)) flat-index remap
__global__ void k_build_h0(const float* __restrict__ hf, const float* __restrict__ hb,
                           const float* __restrict__ cf, const float* __restrict__ cb,
                           float* __restrict__ h0, float* __restrict__ c0) {
  int id = blockIdx.x * 256 + threadIdx.x;  // 65536
  int dir = id >> 15;
  int b = (id >> 9) & 63;
  int j = id & 511;
  h0[id] = dir ? hb[b * EH + j] : hf[b * EH + j];
  c0[id] = dir ? cb[b * EH + j] : cf[b * EH + j];
}

// scores[s,b] = dot(hs[s,b,:], q[b,:]); softmax over b (axis=1 in reference!)
__global__ __launch_bounds__(256) void k_scores(
    const float* __restrict__ hs, const float* __restrict__ q,
    float* __restrict__ attw) {
  int s = blockIdx.x;
  int tid = threadIdx.x;
  int b = tid >> 2, l = tid & 3;
  const float* hrow = hs + (long)s * (BB * 1024) + b * 1024;
  const float* qrow = q + b * 1024;
  float p = 0.f;
  for (int d = l; d < 1024; d += 4) p += hrow[d] * qrow[d];
  p += __shfl_xor(p, 1);
  p += __shfl_xor(p, 2);
  __shared__ float sc[64];
  if (l == 0) sc[b] = p;
  __syncthreads();
  if (tid < 64) {
    float v = sc[tid];
    float m = v;
    for (int o = 32; o > 0; o >>= 1) m = fmaxf(m, __shfl_xor(m, o));
    float e = expf(v - m);
    float su = e;
    for (int o = 32; o > 0; o >>= 1) su += __shfl_xor(su, o);
    attw[s * BB + tid] = e / su;
  }
}

// s_t[b,d] = sum_s attw[s,b] * hs[s,b,d]
__global__ void k_st(const float* __restrict__ hs, const float* __restrict__ attw,
                     float* __restrict__ s_t) {
  int id = blockIdx.x * 256 + threadIdx.x;  // 65536
  int b = id >> 10;
  float acc = 0.f;
  for (int s = 0; s < SS; ++s) acc += attw[s * BB + b] * hs[(long)s * (BB * 1024) + id];
  s_t[id] = acc;
}

// fill dec_in cols 1024..2347: e = emb_de[trg[t,b]] then h_prev
__global__ void k_copy_eh(const int* __restrict__ trg_t, const float* __restrict__ emb_de,
                          const float* __restrict__ h_prev, float* __restrict__ dec_in) {
  int id = blockIdx.x * 256 + threadIdx.x;
  if (id >= BB * 1324) return;
  int b = id / 1324, k = id % 1324;
  float v;
  if (k < 300) v = emb_de[(long)trg_t[b] * EE + k];
  else v = h_prev[b * 1024 + (k - 300)];
  dec_in[b * DKPAD + 1024 + k] = v;
}

// in-place log-softmax over vocab for rows 64..3199 of out
__global__ __launch_bounds__(256) void k_logsoftmax(float* __restrict__ out) {
  int r = blockIdx.x;
  float* p = out + (long)(BB + r) * TRGV;
  int tid = threadIdx.x;
  __shared__ float red[256];
  float m = -1e30f;
  for (int i = tid; i < TRGV; i += 256) m = fmaxf(m, p[i]);
  red[tid] = m;
  __syncthreads();
  for (int s = 128; s > 0; s >>= 1) {
    if (tid < s) red[tid] = fmaxf(red[tid], red[tid + s]);
    __syncthreads();
  }
  m = red[0];
  __syncthreads();
  float sum = 0.f;
  for (int i = tid; i < TRGV; i += 256) sum += expf(p[i] - m);
  red[tid] = sum;
  __syncthreads();
  for (int s = 128; s > 0; s >>= 1) {
    if (tid < s) red[tid] += red[tid + s];
    __syncthreads();
  }
  float lse = m + logf(red[0]);
  for (int i = tid; i < TRGV; i += 256) p[i] -= lse;
}

extern "C" void kernel_launch(void* const* d_in, const int* in_sizes, int n_in,
                              void* d_out, int out_size, void* d_ws, size_t ws_size,
                              hipStream_t stream) {
  const int* src = (const int*)d_in[0];
  const int* trg = (const int*)d_in[1];
  const float* emb_en = (const float*)d_in[2];
  const float* emb_de = (const float*)d_in[3];
  const float* eWih_f = (const float*)d_in[4];
  const float* eWhh_f = (const float*)d_in[5];
  const float* eb_f = (const float*)d_in[6];
  const float* eWih_b = (const float*)d_in[7];
  const float* eWhh_b = (const float*)d_in[8];
  const float* eb_b = (const float*)d_in[9];
  const float* dWih = (const float*)d_in[10];
  const float* dWhh = (const float*)d_in[11];
  const float* db = (const float*)d_in[12];
  const float* Wgen = (const float*)d_in[13];
  const float* bgen = (const float*)d_in[14];
  const float* Wi = (const float*)d_in[15];
  const float* Wo = (const float*)d_in[16];
  float* out = (float*)d_out;

  float* p = (float*)d_ws;
  float* x_enc = p; p += SS * BB * EE;          // 960000
  float* xW_f = p; p += (long)SS * BB * 2048;   // 6553600  (reused for Wgen_bf later)
  float* xW_b = p; p += (long)SS * BB * 2048;
  float* hs = p; p += (long)SS * BB * 1024;     // 3276800
  float* hf0 = p; p += BB * EH;
  float* cf = p; p += BB * EH;
  float* hb0 = p; p += BB * EH;
  float* cb = p; p += BB * EH;
  float* hf1 = p; p += BB * EH;
  float* hb1 = p; p += BB * EH;
  float* hd0 = p; p += BB * DH;
  float* hd1 = p; p += BB * DH;
  float* cd = p; p += BB * DH;
  float* qb = p; p += BB * DH;
  float* attw = p; p += SS * BB;
  float* stb = p; p += BB * DH;
  float* dec_in = p; p += BB * DKPAD;           // 151552
  float* Wcat = p; p += (long)4096 * DKPAD;     // 9699328
  __hip_bfloat16* A_bf = (__hip_bfloat16*)p;    // [GMP][GK] bf16 = 3276800 elems
  p += (GMP * GK) / 2;
  // Wgen_bf aliases the xW_f/xW_b region (13.1M floats = 52.4MB >= 47.7MB needed);
  // it's written only after the encoder recurrences are done with xW.
  __hip_bfloat16* Wgen_bf = (__hip_bfloat16*)xW_f;

  dim3 b256(256);
  dim3 b64x4(64, 4);

  // ---- setup ----
  k_embed<<<dim3((SS * BB * EE + 255) / 256), b256, 0, stream>>>(src, emb_en, x_enc);
  k_wcat<<<dim3((int)(((long)4096 * DKPAD + 255) / 256)), b256, 0, stream>>>(dWih, dWhh, Wcat);
  k_zero<<<dim3((4 * BB * EH + 255) / 256), b256, 0, stream>>>(hf0, 4 * BB * EH);
  k_zero<<<dim3((BB * DKPAD + 255) / 256), b256, 0, stream>>>(dec_in, BB * DKPAD);
  k_zero<<<dim3((BB * TRGV + 255) / 256), b256, 0, stream>>>(out, (long)BB * TRGV);  // out[0]=0
  // zero A_bf pad rows 3136..3199
  k_zero_bf<<<dim3(((GMP - GMRE) * GK + 255) / 256), b256, 0, stream>>>(
      A_bf + (long)GMRE * GK, (long)(GMP - GMRE) * GK);

  // ---- encoder input GEMMs ----
  k_gemm_big<<<dim3(2048 / 64, (SS * BB) / 64), b256, 0, stream>>>(
      x_enc, eWih_f, eb_f, xW_f, SS * BB, 2048, EE, 0);
  k_gemm_big<<<dim3(2048 / 64, (SS * BB) / 64), b256, 0, stream>>>(
      x_enc, eWih_b, eb_b, xW_b, SS * BB, 2048, EE, 1);

  // ---- encoder recurrences ----
  {
    float* hp = hf0;
    float* hn = hf1;
    for (int s = 0; s < SS; ++s) {
      k_enc_step<<<dim3(EH / 4), b64x4, 0, stream>>>(
          hp, cf, eWhh_f, xW_f + (long)s * BB * 2048, hn, hs + (long)s * BB * 1024);
      float* t = hp; hp = hn; hn = t;
    }
    float* hbp = hb0;
    float* hbn = hb1;
    for (int s = 0; s < SS; ++s) {
      k_enc_step<<<dim3(EH / 4), b64x4, 0, stream>>>(
          hbp, cb, eWhh_b, xW_b + (long)s * BB * 2048, hbn,
          hs + (long)(SS - 1 - s) * BB * 1024 + EH);
      float* t = hbp; hbp = hbn; hbn = t;
    }
    k_build_h0<<<dim3(256), b256, 0, stream>>>(hp, hbp, cf, cb, hd0, cd);
  }

  // ---- Wgen -> bf16 (xW region now free) ----
  k_tobf16_pad<<<dim3((int)(((long)GNP * GK + 255) / 256)), b256, 0, stream>>>(
      Wgen, Wgen_bf, GNRE, GNP, GK);

  // ---- decoder loop ----
  float* hc = hd0;
  float* hx = hd1;
  for (int t = 0; t < TT - 1; ++t) {
    k_gemm64<<<dim3(DH / 16), b64x4, 0, stream>>>(
        hc, DH, DH, (const float*)nullptr, 0, 0, Wi, DH, qb, DH, 0);
    k_scores<<<dim3(SS), b256, 0, stream>>>(hs, qb, attw);
    k_st<<<dim3(256), b256, 0, stream>>>(hs, attw, stb);
    k_gemm64<<<dim3(DH / 16), b64x4, 0, stream>>>(
        stb, DH, DH, hc, DH, DH, Wo, 2 * DH, dec_in, DKPAD, 1);
    k_copy_eh<<<dim3((BB * 1324 + 255) / 256), b256, 0, stream>>>(
        trg + t * BB, emb_de, hc, dec_in);
    k_dec_step<<<dim3(DH / 4), b64x4, 0, stream>>>(
        dec_in, Wcat, db, cd, hx, A_bf + (long)t * BB * DH);
    float* tmp = hc; hc = hx; hx = tmp;
  }

  // ---- generator: bf16 MFMA GEMM + log-softmax ----
  k_gen_mfma<<<dim3(GNP / 128, GMP / 128), b256, 0, stream>>>(
      A_bf, Wgen_bf, bgen, out + (long)BB * TRGV);
  k_logsoftmax<<<dim3((TT - 1) * BB), b256, 0, stream>>>(out);
}

// Round 4
// 19670.895 us; speedup vs baseline: 1.4071x; 1.2400x over previous
//
#include <hip/hip_runtime.h>
#include <hip/hip_bf16.h>

#define SS 50
#define TT 50
#define BB 64
#define SRCV 36616
#define TRGV 23262
#define EE 300
#define EH 512
#define DH 1024
// decoder concat K: c_t(1024) | e(300) | h(1024) = 2348, padded to 2368 (37*64)
#define DK 2368
#define DK2 4736     // [hi | lo]
#define CK 2048      // ct GEMM K: [s_t | h]
#define CK2 4096
#define QK 1024
#define QK2 2048

// generator GEMM geometry (bf16 MFMA)
#define GMRE 3136
#define GMP 3200
#define GK 1024
#define GNRE TRGV
#define GNP 23296

typedef short bf16x8 __attribute__((ext_vector_type(8)));
typedef float f32x4 __attribute__((ext_vector_type(4)));

__device__ __forceinline__ void glds16(const void* g, void* l) {
  __builtin_amdgcn_global_load_lds(
      (const __attribute__((address_space(1))) void*)g,
      (__attribute__((address_space(3))) void*)l, 16, 0, 0);
}

__device__ __forceinline__ float sigm(float x) { return 1.f / (1.f + expf(-x)); }

__device__ __forceinline__ void split2(float x, __hip_bfloat16& hi, __hip_bfloat16& lo) {
  hi = __float2bfloat16(x);
  lo = __float2bfloat16(x - __bfloat162float(hi));
}

__global__ void k_zero(float* __restrict__ p, long n) {
  long i = (long)blockIdx.x * 256 + threadIdx.x;
  if (i < n) p[i] = 0.f;
}

__global__ void k_zero_bf(__hip_bfloat16* __restrict__ p, long n) {
  long i = (long)blockIdx.x * 256 + threadIdx.x;
  if (i < n) p[i] = __float2bfloat16(0.f);
}

__global__ void k_embed(const int* __restrict__ src, const float* __restrict__ emb,
                        float* __restrict__ x) {
  int id = blockIdx.x * 256 + threadIdx.x;
  if (id >= SS * BB * EE) return;
  int sb = id / EE, e = id % EE;
  x[id] = emb[(long)src[sb] * EE + e];
}

// Wcat2[rp][0:2368]=hi, [2368:4736]=lo; rp=4j+g <- gate row g*1024+j of [dWih|dWhh|0]
__global__ void k_wcat2(const float* __restrict__ Wih, const float* __restrict__ Whh,
                        __hip_bfloat16* __restrict__ Wb) {
  long id = (long)blockIdx.x * 256 + threadIdx.x;
  if (id >= (long)4096 * DK) return;
  int rp = id / DK, k = id % DK;
  int j = rp >> 2, g = rp & 3;
  long s = (long)(g * 1024 + j);
  float v;
  if (k < 1324) v = Wih[s * 1324 + k];
  else if (k < 2348) v = Whh[s * 1024 + (k - 1324)];
  else v = 0.f;
  __hip_bfloat16 hi, lo;
  split2(v, hi, lo);
  Wb[(long)rp * DK2 + k] = hi;
  Wb[(long)rp * DK2 + DK + k] = lo;
}

__global__ void k_dbperm(const float* __restrict__ db, float* __restrict__ dbp) {
  int id = blockIdx.x * 256 + threadIdx.x;
  if (id >= 4096) return;
  int j = id >> 2, g = id & 3;
  dbp[id] = db[g * 1024 + j];
}

// generic fp32 -> [hi|lo] split weight, row-major NxK -> Nx2K
__global__ void k_wsplit2(const float* __restrict__ W, __hip_bfloat16* __restrict__ W2,
                          long N, int K) {
  long id = (long)blockIdx.x * 256 + threadIdx.x;
  if (id >= N * K) return;
  long r = id / K;
  int k = id % K;
  __hip_bfloat16 hi, lo;
  split2(W[id], hi, lo);
  W2[r * 2 * K + k] = hi;
  W2[r * 2 * K + K + k] = lo;
}

// plain bf16 with zero row padding (generator weight)
__global__ void k_tobf16_pad(const float* __restrict__ W, __hip_bfloat16* __restrict__ Wb,
                             long nrow_real, long nrow_pad, int K) {
  long id = (long)blockIdx.x * 256 + threadIdx.x;
  if (id >= nrow_pad * K) return;
  long r = id / K;
  Wb[id] = __float2bfloat16(r < nrow_real ? W[id] : 0.f);
}

// generic tiled fp32 GEMM (encoder input): C[M,N] = A[M,K] * W[N,K]^T (+bias)
__global__ __launch_bounds__(256) void k_gemm_big(
    const float* __restrict__ A, const float* __restrict__ W,
    const float* __restrict__ bias, float* __restrict__ C,
    int M, int N, int K, int rev) {
  __shared__ float As[16][65];
  __shared__ float Bs[16][65];
  int tid = threadIdx.x;
  int tx = tid & 15, ty = tid >> 4;
  int m0 = blockIdx.y * 64, n0 = blockIdx.x * 64;
  int Srows = M >> 6;
  float acc[4][4] = {};
  for (int k0 = 0; k0 < K; k0 += 16) {
    for (int i = 0; i < 4; ++i) {
      int idx = tid + 256 * i;
      int r = idx >> 4, kk = idx & 15;
      int m = m0 + r;
      float v = 0.f;
      if (m < M && k0 + kk < K) {
        int ar = rev ? (((Srows - 1 - (m >> 6)) << 6) + (m & 63)) : m;
        v = A[(long)ar * K + k0 + kk];
      }
      As[kk][r] = v;
    }
    for (int i = 0; i < 4; ++i) {
      int idx = tid + 256 * i;
      int r = idx >> 4, kk = idx & 15;
      int n = n0 + r;
      float v = 0.f;
      if (n < N && k0 + kk < K) v = W[(long)n * K + k0 + kk];
      Bs[kk][r] = v;
    }
    __syncthreads();
    for (int kk = 0; kk < 16; ++kk) {
      float a[4], bv[4];
      for (int r = 0; r < 4; ++r) a[r] = As[kk][ty * 4 + r];
      for (int c = 0; c < 4; ++c) bv[c] = Bs[kk][tx * 4 + c];
      for (int r = 0; r < 4; ++r)
        for (int c = 0; c < 4; ++c) acc[r][c] += a[r] * bv[c];
    }
    __syncthreads();
  }
  for (int r = 0; r < 4; ++r) {
    int m = m0 + ty * 4 + r;
    if (m >= M) continue;
    for (int c = 0; c < 4; ++c) {
      int n = n0 + tx * 4 + c;
      if (n >= N) continue;
      float v = acc[r][c];
      if (bias) v += bias[n];
      C[(long)m * N + n] = v;
    }
  }
}

// ---- M=64 split-bf16 MFMA GEMM: out[64,N] = (Ah+Al)[64,K] @ (Wh+Wl)[N,K]^T ----
// A stored [64][2K] = [Ah|Al]; W stored [N][2K] = [Wh|Wl].
// 3 passes: Ah*Wh + Al*Wh + Ah*Wl (fp32 acc).
// grid = N/128 blocks, 256 thr (wave w owns n-cols w*32..+31).
// OUTMODE 0: f32 q out (ld 1024). OUTMODE 1: tanh -> split into dec_in2 c_t slots.
// COPY (q kernel): fill dec_in2 e-slots (split of emb) and h-slots (from A=[hh|hl]).
template<int K, int OUTMODE, bool COPY>
__global__ __launch_bounds__(256) void k64_mfma(
    const __hip_bfloat16* __restrict__ A, const __hip_bfloat16* __restrict__ W,
    float* __restrict__ qout, const int* __restrict__ trg_t,
    const float* __restrict__ emb_de, __hip_bfloat16* __restrict__ dec_in2) {
  __shared__ __hip_bfloat16 As[64 * 64];    // 8 KB
  __shared__ __hip_bfloat16 Bs[128 * 64];   // 16 KB
  int tid = threadIdx.x, lane = tid & 63, w = tid >> 6;
  int n0 = blockIdx.x * 128;

  if (COPY) {
    int r0 = blockIdx.x * 8;
    for (int i = tid; i < 8 * 1024; i += 256) {
      int r = r0 + (i >> 10), j = i & 1023;
      dec_in2[r * DK2 + 1324 + j] = A[r * 2048 + j];            // h hi
      dec_in2[r * DK2 + DK + 1324 + j] = A[r * 2048 + 1024 + j]; // h lo
    }
    for (int i = tid; i < 8 * 300; i += 256) {
      int r = r0 + i / 300, j = i % 300;
      __hip_bfloat16 hi, lo;
      split2(emb_de[(long)trg_t[r] * EE + j], hi, lo);
      dec_in2[r * DK2 + 1024 + j] = hi;
      dec_in2[r * DK2 + DK + 1024 + j] = lo;
    }
  }

  char* lA0 = (char*)As + (w * 64) * 16;
  char* lA1 = (char*)As + (4 + w) * 64 * 16;
  char* lB[4];
  for (int j = 0; j < 4; ++j) lB[j] = (char*)Bs + (j * 256 + w * 64) * 16;

  int fr = lane & 15, kq = lane >> 4;
  f32x4 acc[4][2] = {};

  for (int seg = 0; seg < 3; ++seg) {
    const __hip_bfloat16* Ab = (seg == 1) ? A + K : A;
    const __hip_bfloat16* Wb = (seg == 2) ? W + K : W;
    const __hip_bfloat16* gA0 = Ab + lane * (2 * K) + w * 8;
    const __hip_bfloat16* gA1 = Ab + lane * (2 * K) + (4 + w) * 8;
    const __hip_bfloat16* gB[4];
    for (int j = 0; j < 4; ++j)
      gB[j] = Wb + (long)(n0 + (w & 1) * 64 + lane) * (2 * K) + (2 * j + (w >> 1)) * 8;

    for (int k0 = 0; k0 < K; k0 += 64) {
      glds16(gA0 + k0, lA0);
      glds16(gA1 + k0, lA1);
      glds16(gB[0] + k0, lB[0]);
      glds16(gB[1] + k0, lB[1]);
      glds16(gB[2] + k0, lB[2]);
      glds16(gB[3] + k0, lB[3]);
      __syncthreads();
      for (int h = 0; h < 2; ++h) {
        int kc = h * 4 + kq;
        bf16x8 a[4], b[2];
        for (int mi = 0; mi < 4; ++mi)
          a[mi] = *(const bf16x8*)(As + (kc * 64 + mi * 16 + fr) * 8);
        for (int ni = 0; ni < 2; ++ni)
          b[ni] = *(const bf16x8*)(Bs + (kc * 128 + w * 32 + ni * 16 + fr) * 8);
        for (int mi = 0; mi < 4; ++mi)
          for (int ni = 0; ni < 2; ++ni)
            acc[mi][ni] = __builtin_amdgcn_mfma_f32_16x16x32_bf16(a[mi], b[ni], acc[mi][ni], 0, 0, 0);
      }
      __syncthreads();
    }
  }

  for (int mi = 0; mi < 4; ++mi)
    for (int ni = 0; ni < 2; ++ni)
      for (int r = 0; r < 4; ++r) {
        int m = mi * 16 + kq * 4 + r;
        int n = n0 + w * 32 + ni * 16 + fr;
        if (OUTMODE == 0) {
          qout[m * 1024 + n] = acc[mi][ni][r];
        } else {
          __hip_bfloat16 hi, lo;
          split2(tanhf(acc[mi][ni][r]), hi, lo);
          dec_in2[m * DK2 + n] = hi;
          dec_in2[m * DK2 + DK + n] = lo;
        }
      }
}

// ---- decoder gate GEMM (split-bf16) + LSTM pointwise. Wcat2 rows permuted 4j+g ----
// grid 32. Epilogue scatters h hi/lo into A2_q, ct_in2, and h-hi into A_bf[t].
__global__ __launch_bounds__(256) void k_gates_mfma(
    const __hip_bfloat16* dec_in2, const __hip_bfloat16* __restrict__ Wcat2,
    const float* __restrict__ dbp, float* __restrict__ c,
    __hip_bfloat16* __restrict__ h_hi_out, __hip_bfloat16* __restrict__ A2q,
    __hip_bfloat16* __restrict__ ct2) {
  __shared__ __hip_bfloat16 As[64 * 64];
  __shared__ __hip_bfloat16 Bs[128 * 64];
  __shared__ float Gs[64 * 128];
  int tid = threadIdx.x, lane = tid & 63, w = tid >> 6;
  int n0 = blockIdx.x * 128;

  char* lA0 = (char*)As + (w * 64) * 16;
  char* lA1 = (char*)As + (4 + w) * 64 * 16;
  char* lB[4];
  for (int j = 0; j < 4; ++j) lB[j] = (char*)Bs + (j * 256 + w * 64) * 16;

  int fr = lane & 15, kq = lane >> 4;
  f32x4 acc[4][2] = {};

  for (int seg = 0; seg < 3; ++seg) {
    const __hip_bfloat16* Ab = (seg == 1) ? dec_in2 + DK : dec_in2;
    const __hip_bfloat16* Wb = (seg == 2) ? Wcat2 + DK : Wcat2;
    const __hip_bfloat16* gA0 = Ab + lane * DK2 + w * 8;
    const __hip_bfloat16* gA1 = Ab + lane * DK2 + (4 + w) * 8;
    const __hip_bfloat16* gB[4];
    for (int j = 0; j < 4; ++j)
      gB[j] = Wb + (long)(n0 + (w & 1) * 64 + lane) * DK2 + (2 * j + (w >> 1)) * 8;

    for (int k0 = 0; k0 < DK; k0 += 64) {
      glds16(gA0 + k0, lA0);
      glds16(gA1 + k0, lA1);
      glds16(gB[0] + k0, lB[0]);
      glds16(gB[1] + k0, lB[1]);
      glds16(gB[2] + k0, lB[2]);
      glds16(gB[3] + k0, lB[3]);
      __syncthreads();
      for (int h = 0; h < 2; ++h) {
        int kc = h * 4 + kq;
        bf16x8 a[4], b[2];
        for (int mi = 0; mi < 4; ++mi)
          a[mi] = *(const bf16x8*)(As + (kc * 64 + mi * 16 + fr) * 8);
        for (int ni = 0; ni < 2; ++ni)
          b[ni] = *(const bf16x8*)(Bs + (kc * 128 + w * 32 + ni * 16 + fr) * 8);
        for (int mi = 0; mi < 4; ++mi)
          for (int ni = 0; ni < 2; ++ni)
            acc[mi][ni] = __builtin_amdgcn_mfma_f32_16x16x32_bf16(a[mi], b[ni], acc[mi][ni], 0, 0, 0);
      }
      __syncthreads();
    }
  }

  for (int mi = 0; mi < 4; ++mi)
    for (int ni = 0; ni < 2; ++ni)
      for (int r = 0; r < 4; ++r)
        Gs[(mi * 16 + kq * 4 + r) * 128 + w * 32 + ni * 16 + fr] = acc[mi][ni][r];
  __syncthreads();

  for (int i = tid; i < 64 * 32; i += 256) {
    int b = i >> 5, jl = i & 31;
    int nb = 4 * jl;
    float gi = Gs[b * 128 + nb + 0] + dbp[n0 + nb + 0];
    float gf = Gs[b * 128 + nb + 1] + dbp[n0 + nb + 1];
    float gg = Gs[b * 128 + nb + 2] + dbp[n0 + nb + 2];
    float go = Gs[b * 128 + nb + 3] + dbp[n0 + nb + 3];
    int j = (n0 >> 2) + jl;
    float ii = sigm(gi), ff = sigm(gf), gt = tanhf(gg), oo = sigm(go);
    float cn = ff * c[b * 1024 + j] + ii * gt;
    float hn = oo * tanhf(cn);
    c[b * 1024 + j] = cn;
    __hip_bfloat16 hi, lo;
    split2(hn, hi, lo);
    h_hi_out[b * 1024 + j] = hi;
    A2q[b * QK2 + j] = hi;
    A2q[b * QK2 + QK + j] = lo;
    ct2[b * CK2 + 1024 + j] = hi;
    ct2[b * CK2 + CK + 1024 + j] = lo;
  }
}

// ---- bf16 MFMA generator GEMM (128x128 tile) ----
__global__ __launch_bounds__(256) void k_gen_mfma(
    const __hip_bfloat16* __restrict__ A, const __hip_bfloat16* __restrict__ Bw,
    const float* __restrict__ bias, float* __restrict__ C) {
  __shared__ __hip_bfloat16 As[128 * 32];
  __shared__ __hip_bfloat16 Bs[128 * 32];
  int tid = threadIdx.x;
  int lane = tid & 63, w = tid >> 6;
  long m0 = (long)blockIdx.y * 128, n0 = (long)blockIdx.x * 128;

  int srow = lane >> 2;
  int scol = (lane & 3) * 8;
  const __hip_bfloat16* gA0 = A + (m0 + w * 32 + srow) * GK + scol;
  const __hip_bfloat16* gA1 = gA0 + 16 * GK;
  const __hip_bfloat16* gB0 = Bw + (n0 + w * 32 + srow) * GK + scol;
  const __hip_bfloat16* gB1 = gB0 + 16 * GK;
  char* lA0 = (char*)As + w * 2048;
  char* lA1 = lA0 + 1024;
  char* lB0 = (char*)Bs + w * 2048;
  char* lB1 = lB0 + 1024;

  int wm = (w >> 1) * 64, wn = (w & 1) * 64;
  int fr = lane & 15;
  int kc = (lane >> 4) * 8;
  f32x4 acc[4][4] = {};

  for (int kt = 0; kt < GK / 32; ++kt) {
    int k0 = kt * 32;
    glds16(gA0 + k0, lA0);
    glds16(gA1 + k0, lA1);
    glds16(gB0 + k0, lB0);
    glds16(gB1 + k0, lB1);
    __syncthreads();
    bf16x8 a[4], b[4];
    for (int mi = 0; mi < 4; ++mi)
      a[mi] = *(const bf16x8*)(As + (wm + mi * 16 + fr) * 32 + kc);
    for (int ni = 0; ni < 4; ++ni)
      b[ni] = *(const bf16x8*)(Bs + (wn + ni * 16 + fr) * 32 + kc);
    for (int mi = 0; mi < 4; ++mi)
      for (int ni = 0; ni < 4; ++ni)
        acc[mi][ni] = __builtin_amdgcn_mfma_f32_16x16x32_bf16(a[mi], b[ni], acc[mi][ni], 0, 0, 0);
    __syncthreads();
  }

  for (int mi = 0; mi < 4; ++mi) {
    for (int ni = 0; ni < 4; ++ni) {
      int n = (int)n0 + wn + ni * 16 + (lane & 15);
      if (n >= GNRE) continue;
      float bv = bias[n];
      for (int r = 0; r < 4; ++r) {
        int m = (int)m0 + wm + mi * 16 + (lane >> 4) * 4 + r;
        if (m < GMRE) C[(long)m * TRGV + n] = acc[mi][ni][r] + bv;
      }
    }
  }
}

// encoder LSTM step, both directions in one launch (blockIdx.y = dir)
__global__ __launch_bounds__(256) void k_enc_step2(
    const float* __restrict__ hpf, float* __restrict__ cfp,
    const float* __restrict__ Whf, const float* __restrict__ xWf,
    float* __restrict__ hnf, float* __restrict__ hsf,
    const float* __restrict__ hpb, float* __restrict__ cbp,
    const float* __restrict__ Whb, const float* __restrict__ xWb,
    float* __restrict__ hnb, float* __restrict__ hsb) {
  const float* h_prev;
  float* c;
  const float* W_hh;
  const float* xW;
  float* h_next;
  float* hs_dst;
  if (blockIdx.y == 0) {
    h_prev = hpf; c = cfp; W_hh = Whf; xW = xWf; h_next = hnf; hs_dst = hsf;
  } else {
    h_prev = hpb; c = cbp; W_hh = Whb; xW = xWb; h_next = hnb; hs_dst = hsb;
  }
  __shared__ float As[64][65];
  __shared__ float Ws[16][64];
  int b = threadIdx.x, jj = threadIdx.y;
  int tid = jj * 64 + b;
  int j0 = blockIdx.x * 4;
  float acc[4] = {0.f, 0.f, 0.f, 0.f};
  for (int k0 = 0; k0 < EH; k0 += 64) {
    for (int i = 0; i < 16; ++i) {
      int idx = tid + 256 * i;
      int r = idx >> 6, kk = idx & 63;
      As[r][kk] = h_prev[r * EH + k0 + kk];
    }
    for (int i = 0; i < 4; ++i) {
      int idx = tid + 256 * i;
      int r = idx >> 6, kk = idx & 63;
      int grow = j0 + (r & 3) + (r >> 2) * EH;
      Ws[r][kk] = W_hh[grow * EH + k0 + kk];
    }
    __syncthreads();
    for (int kk = 0; kk < 64; ++kk) {
      float a = As[b][kk];
      acc[0] += a * Ws[jj][kk];
      acc[1] += a * Ws[4 + jj][kk];
      acc[2] += a * Ws[8 + jj][kk];
      acc[3] += a * Ws[12 + jj][kk];
    }
    __syncthreads();
  }
  int j = j0 + jj;
  float gi = acc[0] + xW[b * 2048 + j];
  float gf = acc[1] + xW[b * 2048 + j + 512];
  float gg = acc[2] + xW[b * 2048 + j + 1024];
  float go = acc[3] + xW[b * 2048 + j + 1536];
  float ii = sigm(gi), ff = sigm(gf), gt = tanhf(gg), oo = sigm(go);
  float cn = ff * c[b * EH + j] + ii * gt;
  float hn = oo * tanhf(cn);
  c[b * EH + j] = cn;
  h_next[b * EH + j] = hn;
  hs_dst[b * 1024 + j] = hn;
}

// decoder initial state: c0 fp32; h0 split scattered into A2_q and ct_in2
__global__ void k_build_h0(const float* __restrict__ hf, const float* __restrict__ hb,
                           const float* __restrict__ cf, const float* __restrict__ cb,
                           float* __restrict__ c0, __hip_bfloat16* __restrict__ A2q,
                           __hip_bfloat16* __restrict__ ct2) {
  int id = blockIdx.x * 256 + threadIdx.x;  // 65536
  int dir = id >> 15;
  int b = (id >> 9) & 63;
  int j = id & 511;
  float hv = dir ? hb[b * EH + j] : hf[b * EH + j];
  c0[id] = dir ? cb[b * EH + j] : cf[b * EH + j];
  int bb = id >> 10, cc = id & 1023;
  __hip_bfloat16 hi, lo;
  split2(hv, hi, lo);
  A2q[bb * QK2 + cc] = hi;
  A2q[bb * QK2 + QK + cc] = lo;
  ct2[bb * CK2 + 1024 + cc] = hi;
  ct2[bb * CK2 + CK + 1024 + cc] = lo;
}

// scores[s,b] = dot(hs[s,b,:], q[b,:]); softmax over b (axis=1 in reference!)
__global__ __launch_bounds__(256) void k_scores(
    const float* __restrict__ hs, const float* __restrict__ q,
    float* __restrict__ attw) {
  int s = blockIdx.x;
  int tid = threadIdx.x;
  int b = tid >> 2, l = tid & 3;
  const float* hrow = hs + (long)s * (BB * 1024) + b * 1024;
  const float* qrow = q + b * 1024;
  float p = 0.f;
  for (int d = l; d < 1024; d += 4) p += hrow[d] * qrow[d];
  p += __shfl_xor(p, 1);
  p += __shfl_xor(p, 2);
  __shared__ float sc[64];
  if (l == 0) sc[b] = p;
  __syncthreads();
  if (tid < 64) {
    float v = sc[tid];
    float m = v;
    for (int o = 32; o > 0; o >>= 1) m = fmaxf(m, __shfl_xor(m, o));
    float e = expf(v - m);
    float su = e;
    for (int o = 32; o > 0; o >>= 1) su += __shfl_xor(su, o);
    attw[s * BB + tid] = e / su;
  }
}

// s_t[b,d] = sum_s attw[s,b] * hs[s,b,d] -> ct_in2 s-slots (split)
__global__ void k_st(const float* __restrict__ hs, const float* __restrict__ attw,
                     __hip_bfloat16* __restrict__ ct2) {
  int id = blockIdx.x * 256 + threadIdx.x;  // 65536
  int b = id >> 10, d = id & 1023;
  float acc = 0.f;
  for (int s = 0; s < SS; ++s) acc += attw[s * BB + b] * hs[(long)s * (BB * 1024) + id];
  __hip_bfloat16 hi, lo;
  split2(acc, hi, lo);
  ct2[b * CK2 + d] = hi;
  ct2[b * CK2 + CK + d] = lo;
}

// in-place log-softmax over vocab for rows 64..3199 of out
__global__ __launch_bounds__(256) void k_logsoftmax(float* __restrict__ out) {
  int r = blockIdx.x;
  float* p = out + (long)(BB + r) * TRGV;
  int tid = threadIdx.x;
  __shared__ float red[256];
  float m = -1e30f;
  for (int i = tid; i < TRGV; i += 256) m = fmaxf(m, p[i]);
  red[tid] = m;
  __syncthreads();
  for (int s = 128; s > 0; s >>= 1) {
    if (tid < s) red[tid] = fmaxf(red[tid], red[tid + s]);
    __syncthreads();
  }
  m = red[0];
  __syncthreads();
  float sum = 0.f;
  for (int i = tid; i < TRGV; i += 256) sum += expf(p[i] - m);
  red[tid] = sum;
  __syncthreads();
  for (int s = 128; s > 0; s >>= 1) {
    if (tid < s) red[tid] += red[tid + s];
    __syncthreads();
  }
  float lse = m + logf(red[0]);
  for (int i = tid; i < TRGV; i += 256) p[i] -= lse;
}

extern "C" void kernel_launch(void* const* d_in, const int* in_sizes, int n_in,
                              void* d_out, int out_size, void* d_ws, size_t ws_size,
                              hipStream_t stream) {
  const int* src = (const int*)d_in[0];
  const int* trg = (const int*)d_in[1];
  const float* emb_en = (const float*)d_in[2];
  const float* emb_de = (const float*)d_in[3];
  const float* eWih_f = (const float*)d_in[4];
  const float* eWhh_f = (const float*)d_in[5];
  const float* eb_f = (const float*)d_in[6];
  const float* eWih_b = (const float*)d_in[7];
  const float* eWhh_b = (const float*)d_in[8];
  const float* eb_b = (const float*)d_in[9];
  const float* dWih = (const float*)d_in[10];
  const float* dWhh = (const float*)d_in[11];
  const float* db = (const float*)d_in[12];
  const float* Wgen = (const float*)d_in[13];
  const float* bgen = (const float*)d_in[14];
  const float* Wi = (const float*)d_in[15];
  const float* Wo = (const float*)d_in[16];
  float* out = (float*)d_out;

  float* p = (float*)d_ws;
  float* x_enc = p; p += SS * BB * EE;
  float* xW_f = p; p += (long)SS * BB * 2048;   // reused for Wgen_bf later
  float* xW_b = p; p += (long)SS * BB * 2048;
  float* hs = p; p += (long)SS * BB * 1024;
  float* hf0 = p; p += BB * EH;
  float* cf = p; p += BB * EH;
  float* hb0 = p; p += BB * EH;
  float* cb = p; p += BB * EH;
  float* hf1 = p; p += BB * EH;
  float* hb1 = p; p += BB * EH;
  float* cd = p; p += BB * DH;
  float* qb = p; p += BB * DH;
  float* attw = p; p += SS * BB;
  float* dbp = p; p += 4096;
  __hip_bfloat16* A_bf = (__hip_bfloat16*)p; p += (GMP * GK) / 2;
  __hip_bfloat16* A2_q = (__hip_bfloat16*)p; p += (BB * QK2) / 2;
  __hip_bfloat16* ct_in2 = (__hip_bfloat16*)p; p += (BB * CK2) / 2;
  __hip_bfloat16* dec_in2 = (__hip_bfloat16*)p; p += (BB * DK2) / 2;
  __hip_bfloat16* Wi2 = (__hip_bfloat16*)p; p += (DH * QK2) / 2;
  __hip_bfloat16* Wo2 = (__hip_bfloat16*)p; p += (DH * CK2) / 2;
  __hip_bfloat16* Wcat2 = (__hip_bfloat16*)p; p += ((long)4096 * DK2) / 2;
  __hip_bfloat16* Wgen_bf = (__hip_bfloat16*)xW_f;  // written after encoder

  dim3 b256(256);
  dim3 b64x4(64, 4);

  // ---- setup / weight conversion ----
  k_embed<<<dim3((SS * BB * EE + 255) / 256), b256, 0, stream>>>(src, emb_en, x_enc);
  k_wcat2<<<dim3((int)(((long)4096 * DK + 255) / 256)), b256, 0, stream>>>(dWih, dWhh, Wcat2);
  k_dbperm<<<dim3(16), b256, 0, stream>>>(db, dbp);
  k_wsplit2<<<dim3((int)(((long)DH * QK + 255) / 256)), b256, 0, stream>>>(Wi, Wi2, DH, QK);
  k_wsplit2<<<dim3((int)(((long)DH * CK + 255) / 256)), b256, 0, stream>>>(Wo, Wo2, DH, CK);
  k_zero<<<dim3((6 * BB * EH + 255) / 256), b256, 0, stream>>>(hf0, 6 * BB * EH);
  k_zero<<<dim3((BB * TRGV + 255) / 256), b256, 0, stream>>>(out, (long)BB * TRGV);  // out[0]=0
  k_zero_bf<<<dim3((BB * DK2 + 255) / 256), b256, 0, stream>>>(dec_in2, (long)BB * DK2);
  k_zero_bf<<<dim3(((GMP - GMRE) * GK + 255) / 256), b256, 0, stream>>>(
      A_bf + (long)GMRE * GK, (long)(GMP - GMRE) * GK);

  // ---- encoder input GEMMs ----
  k_gemm_big<<<dim3(2048 / 64, (SS * BB) / 64), b256, 0, stream>>>(
      x_enc, eWih_f, eb_f, xW_f, SS * BB, 2048, EE, 0);
  k_gemm_big<<<dim3(2048 / 64, (SS * BB) / 64), b256, 0, stream>>>(
      x_enc, eWih_b, eb_b, xW_b, SS * BB, 2048, EE, 1);

  // ---- encoder recurrences (both dirs per launch) ----
  {
    float* hp = hf0; float* hn = hf1;
    float* hbp = hb0; float* hbn = hb1;
    for (int s = 0; s < SS; ++s) {
      k_enc_step2<<<dim3(EH / 4, 2), b64x4, 0, stream>>>(
          hp, cf, eWhh_f, xW_f + (long)s * BB * 2048, hn, hs + (long)s * BB * 1024,
          hbp, cb, eWhh_b, xW_b + (long)s * BB * 2048, hbn,
          hs + (long)(SS - 1 - s) * BB * 1024 + EH);
      float* t = hp; hp = hn; hn = t;
      t = hbp; hbp = hbn; hbn = t;
    }
    k_build_h0<<<dim3(256), b256, 0, stream>>>(hp, hbp, cf, cb, cd, A2_q, ct_in2);
  }

  // ---- Wgen -> bf16 (xW region now free) ----
  k_tobf16_pad<<<dim3((int)(((long)GNP * GK + 255) / 256)), b256, 0, stream>>>(
      Wgen, Wgen_bf, GNRE, GNP, GK);

  // ---- decoder loop (5 kernels/step; GEMMs are split-bf16 MFMA = fp32-accurate) ----
  for (int t = 0; t < TT - 1; ++t) {
    k64_mfma<QK, 0, true><<<dim3(8), b256, 0, stream>>>(
        A2_q, Wi2, qb, trg + t * BB, emb_de, dec_in2);
    k_scores<<<dim3(SS), b256, 0, stream>>>(hs, qb, attw);
    k_st<<<dim3(256), b256, 0, stream>>>(hs, attw, ct_in2);
    k64_mfma<CK, 1, false><<<dim3(8), b256, 0, stream>>>(
        ct_in2, Wo2, nullptr, nullptr, nullptr, dec_in2);
    k_gates_mfma<<<dim3(32), b256, 0, stream>>>(
        dec_in2, Wcat2, dbp, cd, A_bf + (long)t * BB * DH, A2_q, ct_in2);
  }

  // ---- generator: bf16 MFMA GEMM + log-softmax ----
  k_gen_mfma<<<dim3(GNP / 128, GMP / 128), b256, 0, stream>>>(
      A_bf, Wgen_bf, bgen, out + (long)BB * TRGV);
  k_logsoftmax<<<dim3((TT - 1) * BB), b256, 0, stream>>>(out);
}